// Round 1
// 107.853 us; speedup vs baseline: 1.0041x; 1.0041x over previous
//
#include <hip/hip_runtime.h>
#include <stdint.h>

// PoissonNeuronTransform — bit-exact vs the harness's NUMPY reference (ref=np).
// Validated (absmax 0.0, R11-R18): threefry2x32 partitionable bits, uniform
// bit-trick, fdlibm log1pf port (dead c-branch removed, proof R17), double-
// reciprocal division, +0.002f, sequential f32 cumsum, early exit (monotone
// RN-fadd), wave-internal ballot lane-refill, LPT (descending-rate) handout.
// Round 19 (perf only): hoisted per-element f64 reciprocal into setup (LDS).
// Round 20 (perf only, THIS ROUND): __launch_bounds__(256, 8).
//   rocprof showed OccupancyPercent 46% == 4 waves/SIMD: VGPR_Count 12
//   granules (~96 regs) sits past the 64-reg occupancy cliff. The kernel is
//   VALU-bound with a fully-serial ARX dep chain (threefry) + lgkm waits at
//   refill; 4 waves/SIMD cannot cover the issue bubbles. Forcing the
//   allocator to 64 VGPRs (8 waves/EU) doubles resident waves. No semantic
//   change -> bit-exact by construction.

static constexpr int      kElems  = 256 * 32 * 128;   // 1048576 = 2^20
static constexpr int      kSpikes = 100;              // NUM_SPIKES
static constexpr int      kBlocks = 2048;             // x256 thr = 8192 waves
static constexpr uint32_t kEPW    = 128;              // elements per wave

__device__ __forceinline__ uint32_t rotl32(uint32_t v, uint32_t d) {
  return (v << d) | (v >> (32u - d));
}

// threefry2x32 with key (0, 42) — matches jax.random.key(42).
__device__ __forceinline__ void threefry2x32_0_42(uint32_t x0, uint32_t x1,
                                                  uint32_t& o0, uint32_t& o1) {
  const uint32_t ks0 = 0u;
  const uint32_t ks1 = 42u;
  const uint32_t ks2 = 0x1BD11BDAu ^ 0u ^ 42u;
  uint32_t a = x0 + ks0;
  uint32_t b = x1 + ks1;
#define TF_ROUND(r) { a += b; b = rotl32(b, (r)); b ^= a; }
  TF_ROUND(13u) TF_ROUND(15u) TF_ROUND(26u) TF_ROUND(6u)
  a += ks1; b += ks2 + 1u;
  TF_ROUND(17u) TF_ROUND(29u) TF_ROUND(16u) TF_ROUND(24u)
  a += ks2; b += ks0 + 2u;
  TF_ROUND(13u) TF_ROUND(15u) TF_ROUND(26u) TF_ROUND(6u)
  a += ks0; b += ks1 + 3u;
  TF_ROUND(17u) TF_ROUND(29u) TF_ROUND(16u) TF_ROUND(24u)
  a += ks1; b += ks2 + 4u;
  TF_ROUND(13u) TF_ROUND(15u) TF_ROUND(26u) TF_ROUND(6u)
  a += ks2; b += ks0 + 5u;
#undef TF_ROUND
  o0 = a; o1 = b;
}

// Branchless fdlibm s_log1pf for x = -m*2^-23, m in [0, 2^23) — bit-exact
// (R12 port) with the c-correction removed (c == +0 on this input set,
// proof R17). One IEEE f32 div remains: s = f/(2+f).
__device__ __forceinline__ float fdlibm_log1pf_nb(float x) {
#pragma clang fp contract(off)
  const float ln2_hi = __uint_as_float(0x3f317180u);
  const float ln2_lo = __uint_as_float(0x3717f7d1u);
  const float Lp1 = __uint_as_float(0x3F2AAAABu);
  const float Lp2 = __uint_as_float(0x3ECCCCCDu);
  const float Lp3 = __uint_as_float(0x3E924925u);
  const float Lp4 = __uint_as_float(0x3E638E29u);
  const float Lp5 = __uint_as_float(0x3E3A3325u);
  const float Lp6 = __uint_as_float(0x3E1CD04Fu);
  const float Lp7 = __uint_as_float(0x3E178897u);

  uint32_t hx = __float_as_uint(x);
  uint32_t ax = hx & 0x7fffffffu;

  float u = 1.0f + x;
  uint32_t hu = __float_as_uint(u);
  int k = (int)(hu >> 23) - 127;
  uint32_t m = hu & 0x007fffffu;
  bool half = (m >= 0x3504f7u);
  int k2 = half ? (k + 1) : k;
  float u2 = __uint_as_float(m | (half ? 0x3f000000u : 0x3f800000u));
  float f2 = u2 - 1.0f;

  bool cond0 = ((int32_t)hx <= (int32_t)0xbe95f61fu);
  float kf = cond0 ? 0.0f : (float)k2;
  float ff = cond0 ? x : f2;

  float hfsq = (0.5f * ff) * ff;
  float s = ff / (2.0f + ff);             // f32 IEEE div (the only one left)
  float z = s * s;
  float R = z * (Lp1 + z * (Lp2 + z * (Lp3 + z * (Lp4 +
            z * (Lp5 + z * (Lp6 + z * Lp7))))));
  float lowsum = s * (hfsq + R) + kf * ln2_lo;
  float res = kf * ln2_hi - ((hfsq - lowsum) - ff);

  float tiny2 = x - (x * x) * 0.5f;
  res = (ax < 0x38000000u) ? ((ax < 0x33800000u) ? x : tiny2) : res;
  return res;
}

__global__ void __launch_bounds__(256, 8) poisson_count_kernel(
    const float* __restrict__ rates, int* __restrict__ out) {
#pragma clang fp contract(off)
  __shared__ uint32_t pool_idx[4][kEPW];   // local element index (LPT order)
  __shared__ double   pool_inv[4][kEPW];   // hoisted 1.0/(double)rate
  int wslot = (int)threadIdx.x >> 6;
  int lane  = (int)threadIdx.x & 63;
  int wid   = blockIdx.x * 4 + wslot;
  uint32_t base = (uint32_t)wid * kEPW;
  uint64_t lmask_lt = (1ull << lane) - 1ull;

  // ---- one-time setup: LPT buckets + hoisted f64 reciprocals ----
  {
    float r0 = rates[base + (uint32_t)lane];
    float r1 = rates[base + 64u + (uint32_t)lane];
    int q0 = (int)(r0 * 0.4f); q0 = q0 > 7 ? 7 : q0;
    int q1 = (int)(r1 * 0.4f); q1 = q1 > 7 ? 7 : q1;
    int b0 = 7 - q0, b1 = 7 - q1;          // bucket 0 = highest rates
    uint32_t off = 0, pos0 = 0, pos1 = 0;
#pragma unroll
    for (int b = 0; b < 8; ++b) {
      uint64_t mA = __ballot(b0 == b);
      uint64_t mB = __ballot(b1 == b);
      uint32_t cA = (uint32_t)__popcll(mA);
      if (b0 == b) pos0 = off + (uint32_t)__popcll(mA & lmask_lt);
      if (b1 == b) pos1 = off + cA + (uint32_t)__popcll(mB & lmask_lt);
      off += cA + (uint32_t)__popcll(mB);
    }
    pool_idx[wslot][pos0] = (uint32_t)lane;
    pool_inv[wslot][pos0] = 1.0 / (double)r0;   // CR f64 reciprocal, hoisted
    pool_idx[wslot][pos1] = 64u + (uint32_t)lane;
    pool_inv[wslot][pos1] = 1.0 / (double)r1;
  }
  __syncthreads();

  // ---- main loop: R14/R17/R18 structure; refill = two LDS reads ----
  uint32_t next = 0;                       // wave-uniform: elements handed out
  uint32_t o = 0;
  float run = 0.0f;
  int cnt = 0, s = 0;
  double inv_d = 0.0;
  bool active = false;

  while (true) {
    uint64_t needmask = __ballot(!active);
    if (needmask != 0ull) {
      uint32_t avail = kEPW - next;
      if (avail != 0u) {
        if (!active) {
          uint32_t rank = (uint32_t)__popcll(needmask & lmask_lt);
          if (rank < avail) {
            uint32_t slot = next + rank;
            o = base + pool_idx[wslot][slot];
            inv_d = pool_inv[wslot][slot];
            run = 0.0f; cnt = 0; s = 0;
            active = true;
          }
        }
        uint32_t nneed = (uint32_t)__popcll(needmask);
        next += (nneed < avail) ? nneed : avail;
      } else if (needmask == ~0ull) {
        break;                             // pool empty, all lanes idle
      }
    }

    if (active) {
      uint32_t j = ((uint32_t)s << 20) + o;   // kElems == 2^20
      uint32_t b1, b2;
      threefry2x32_0_42(0u, j, b1, b2);
      uint32_t bits = b1 ^ b2;
      float uu = __uint_as_float((bits >> 9) | 0x3f800000u) - 1.0f;  // [0, 1)
      float expo = -fdlibm_log1pf_nb(-uu);
      float q = (float)((double)expo * inv_d);  // == expo / rate (IEEE f32)
      float delta = q + 0.002f;
      run = run + delta;                   // sequential f32 cumsum
      cnt += (run < 1.0f) ? 1 : 0;
      s += 1;
      if (!(run < 1.0f) || s == kSpikes) { // early exit (monotone) or cap
        out[o] = cnt;
        active = false;
      }
    }
  }
}

extern "C" void kernel_launch(void* const* d_in, const int* in_sizes, int n_in,
                              void* d_out, int out_size, void* d_ws, size_t ws_size,
                              hipStream_t stream) {
  const float* rates = (const float*)d_in[0];
  int* out = (int*)d_out;
  (void)in_sizes; (void)n_in; (void)out_size; (void)d_ws; (void)ws_size;
  poisson_count_kernel<<<kBlocks, 256, 0, stream>>>(rates, out);
}

// Round 3
// 106.290 us; speedup vs baseline: 1.0189x; 1.0147x over previous
//
#include <hip/hip_runtime.h>
#include <stdint.h>

// PoissonNeuronTransform — bit-exact vs the harness's NUMPY reference (ref=np).
// Validated (absmax 0.0, R11-R18): threefry2x32 partitionable bits, uniform
// bit-trick, fdlibm log1pf port (dead c-branch removed, proof R17), double-
// reciprocal division, +0.002f, sequential f32 cumsum, early exit (monotone
// RN-fadd), wave-internal ballot lane-refill, LPT (descending-rate) handout.
// R19: hoisted per-element f64 reciprocal into setup (LDS).
// R20: __launch_bounds__(256,8) — NO-OP (VGPR_Count=12 is raw; never limited).
// R21 (perf only; resubmitted R22 after infra failure): amortize the
//   straggler tail + drop cnt. Instruction audit showed per-wave makespan
//   ~30 rounds vs ideal 22 with kEPW=128: pool dries at ~round 18, then the
//   longest elements (rate~20, ~25-30 sequential evals) run with few active
//   lanes while the full ~150-inst body still issues => ~28% issue waste.
//   The straggler bound is absolute (longest element's sequential cumsum),
//   ideal rounds scale with pool size => kEPW=256 (1024 blocks): ideal ~43
//   rounds, makespan ~45, utilization 72%->~96%. Also: cnt register
//   eliminated — monotone run implies cnt == (run<1 ? s : s-1) at exit.
//   Same per-element math, bit-exact by construction.

static constexpr int      kElems  = 256 * 32 * 128;   // 1048576 = 2^20
static constexpr int      kSpikes = 100;              // NUM_SPIKES
static constexpr int      kBlocks = 1024;             // x256 thr = 4096 waves
static constexpr uint32_t kEPW    = 256;              // elements per wave

__device__ __forceinline__ uint32_t rotl32(uint32_t v, uint32_t d) {
  return (v << d) | (v >> (32u - d));
}

// threefry2x32 with key (0, 42) — matches jax.random.key(42).
__device__ __forceinline__ void threefry2x32_0_42(uint32_t x0, uint32_t x1,
                                                  uint32_t& o0, uint32_t& o1) {
  const uint32_t ks0 = 0u;
  const uint32_t ks1 = 42u;
  const uint32_t ks2 = 0x1BD11BDAu ^ 0u ^ 42u;
  uint32_t a = x0 + ks0;
  uint32_t b = x1 + ks1;
#define TF_ROUND(r) { a += b; b = rotl32(b, (r)); b ^= a; }
  TF_ROUND(13u) TF_ROUND(15u) TF_ROUND(26u) TF_ROUND(6u)
  a += ks1; b += ks2 + 1u;
  TF_ROUND(17u) TF_ROUND(29u) TF_ROUND(16u) TF_ROUND(24u)
  a += ks2; b += ks0 + 2u;
  TF_ROUND(13u) TF_ROUND(15u) TF_ROUND(26u) TF_ROUND(6u)
  a += ks0; b += ks1 + 3u;
  TF_ROUND(17u) TF_ROUND(29u) TF_ROUND(16u) TF_ROUND(24u)
  a += ks1; b += ks2 + 4u;
  TF_ROUND(13u) TF_ROUND(15u) TF_ROUND(26u) TF_ROUND(6u)
  a += ks2; b += ks0 + 5u;
#undef TF_ROUND
  o0 = a; o1 = b;
}

// Branchless fdlibm s_log1pf for x = -m*2^-23, m in [0, 2^23) — bit-exact
// (R12 port) with the c-correction removed (c == +0 on this input set,
// proof R17). One IEEE f32 div remains: s = f/(2+f).
__device__ __forceinline__ float fdlibm_log1pf_nb(float x) {
#pragma clang fp contract(off)
  const float ln2_hi = __uint_as_float(0x3f317180u);
  const float ln2_lo = __uint_as_float(0x3717f7d1u);
  const float Lp1 = __uint_as_float(0x3F2AAAABu);
  const float Lp2 = __uint_as_float(0x3ECCCCCDu);
  const float Lp3 = __uint_as_float(0x3E924925u);
  const float Lp4 = __uint_as_float(0x3E638E29u);
  const float Lp5 = __uint_as_float(0x3E3A3325u);
  const float Lp6 = __uint_as_float(0x3E1CD04Fu);
  const float Lp7 = __uint_as_float(0x3E178897u);

  uint32_t hx = __float_as_uint(x);
  uint32_t ax = hx & 0x7fffffffu;

  float u = 1.0f + x;
  uint32_t hu = __float_as_uint(u);
  int k = (int)(hu >> 23) - 127;
  uint32_t m = hu & 0x007fffffu;
  bool half = (m >= 0x3504f7u);
  int k2 = half ? (k + 1) : k;
  float u2 = __uint_as_float(m | (half ? 0x3f000000u : 0x3f800000u));
  float f2 = u2 - 1.0f;

  bool cond0 = ((int32_t)hx <= (int32_t)0xbe95f61fu);
  float kf = cond0 ? 0.0f : (float)k2;
  float ff = cond0 ? x : f2;

  float hfsq = (0.5f * ff) * ff;
  float s = ff / (2.0f + ff);             // f32 IEEE div (the only one left)
  float z = s * s;
  float R = z * (Lp1 + z * (Lp2 + z * (Lp3 + z * (Lp4 +
            z * (Lp5 + z * (Lp6 + z * Lp7))))));
  float lowsum = s * (hfsq + R) + kf * ln2_lo;
  float res = kf * ln2_hi - ((hfsq - lowsum) - ff);

  float tiny2 = x - (x * x) * 0.5f;
  res = (ax < 0x38000000u) ? ((ax < 0x33800000u) ? x : tiny2) : res;
  return res;
}

__global__ void __launch_bounds__(256) poisson_count_kernel(
    const float* __restrict__ rates, int* __restrict__ out) {
#pragma clang fp contract(off)
  __shared__ uint32_t pool_idx[4][kEPW];   // local element index (LPT order)
  __shared__ double   pool_inv[4][kEPW];   // hoisted 1.0/(double)rate
  int wslot = (int)threadIdx.x >> 6;
  int lane  = (int)threadIdx.x & 63;
  int wid   = blockIdx.x * 4 + wslot;
  uint32_t base = (uint32_t)wid * kEPW;
  uint64_t lmask_lt = (1ull << lane) - 1ull;

  // ---- one-time setup: LPT buckets + hoisted f64 reciprocals ----
  {
    float r[4];
    int   bb[4];
    uint32_t pos[4];
#pragma unroll
    for (int i = 0; i < 4; ++i) {
      r[i] = rates[base + (uint32_t)(i * 64) + (uint32_t)lane];
      int q = (int)(r[i] * 0.4f);
      q = q > 7 ? 7 : q;
      bb[i] = 7 - q;                       // bucket 0 = highest rates
    }
    uint32_t off = 0;
#pragma unroll
    for (int b = 0; b < 8; ++b) {
      uint64_t m0 = __ballot(bb[0] == b);
      uint64_t m1 = __ballot(bb[1] == b);
      uint64_t m2 = __ballot(bb[2] == b);
      uint64_t m3 = __ballot(bb[3] == b);
      uint32_t c0 = (uint32_t)__popcll(m0);
      uint32_t c1 = (uint32_t)__popcll(m1);
      uint32_t c2 = (uint32_t)__popcll(m2);
      uint32_t c3 = (uint32_t)__popcll(m3);
      if (bb[0] == b) pos[0] = off + (uint32_t)__popcll(m0 & lmask_lt);
      if (bb[1] == b) pos[1] = off + c0 + (uint32_t)__popcll(m1 & lmask_lt);
      if (bb[2] == b) pos[2] = off + c0 + c1 + (uint32_t)__popcll(m2 & lmask_lt);
      if (bb[3] == b) pos[3] = off + c0 + c1 + c2 + (uint32_t)__popcll(m3 & lmask_lt);
      off += c0 + c1 + c2 + c3;
    }
#pragma unroll
    for (int i = 0; i < 4; ++i) {
      pool_idx[wslot][pos[i]] = (uint32_t)(i * 64) + (uint32_t)lane;
      pool_inv[wslot][pos[i]] = 1.0 / (double)r[i];   // CR f64 recip, hoisted
    }
  }
  __syncthreads();

  // ---- main loop: ballot lane-refill from wave-local 256-element pool ----
  uint32_t next = 0;                       // wave-uniform: elements handed out
  uint32_t o = 0;
  float run = 0.0f;
  int s = 0;
  double inv_d = 0.0;
  bool active = false;

  while (true) {
    uint64_t needmask = __ballot(!active);
    if (needmask != 0ull) {
      uint32_t avail = kEPW - next;
      if (avail != 0u) {
        if (!active) {
          uint32_t rank = (uint32_t)__popcll(needmask & lmask_lt);
          if (rank < avail) {
            uint32_t slot = next + rank;
            o = base + pool_idx[wslot][slot];
            inv_d = pool_inv[wslot][slot];
            run = 0.0f; s = 0;
            active = true;
          }
        }
        uint32_t nneed = (uint32_t)__popcll(needmask);
        next += (nneed < avail) ? nneed : avail;
      } else if (needmask == ~0ull) {
        break;                             // pool empty, all lanes idle
      }
    }

    if (active) {
      uint32_t j = ((uint32_t)s << 20) + o;   // kElems == 2^20
      uint32_t b1, b2;
      threefry2x32_0_42(0u, j, b1, b2);
      uint32_t bits = b1 ^ b2;
      float uu = __uint_as_float((bits >> 9) | 0x3f800000u) - 1.0f;  // [0, 1)
      float expo = -fdlibm_log1pf_nb(-uu);
      float q = (float)((double)expo * inv_d);  // == expo / rate (IEEE f32)
      float delta = q + 0.002f;
      run = run + delta;                   // sequential f32 cumsum
      s += 1;
      bool below = (run < 1.0f);
      if (!below || s == kSpikes) {        // early exit (monotone) or cap
        // cnt == s when run still < 1 (cap exit), else s-1: every earlier
        // eval had run < 1 (monotone nondecreasing RN cumsum, delta>0).
        out[o] = below ? s : (s - 1);
        active = false;
      }
    }
  }
}

extern "C" void kernel_launch(void* const* d_in, const int* in_sizes, int n_in,
                              void* d_out, int out_size, void* d_ws, size_t ws_size,
                              hipStream_t stream) {
  const float* rates = (const float*)d_in[0];
  int* out = (int*)d_out;
  (void)in_sizes; (void)n_in; (void)out_size; (void)d_ws; (void)ws_size;
  poisson_count_kernel<<<kBlocks, 256, 0, stream>>>(rates, out);
}

// Round 4
// 103.204 us; speedup vs baseline: 1.0494x; 1.0299x over previous
//
#include <hip/hip_runtime.h>
#include <stdint.h>

// PoissonNeuronTransform — bit-exact vs the harness's NUMPY reference (ref=np).
// Validated (absmax 0.0, R11-R18): threefry2x32 partitionable bits, uniform
// bit-trick, fdlibm log1pf port (dead c-branch removed, proof R17), double-
// reciprocal division, +0.002f, sequential f32 cumsum, early exit (monotone
// RN-fadd), wave-internal ballot lane-refill, LPT (descending-rate) handout.
// R19: hoisted per-element f64 reciprocal into setup (LDS).
// R20: __launch_bounds__(256,8) — NO-OP (VGPR_Count=12 raw; never limited).
// R21/22: kEPW=256 (1024 blocks) straggler amortization + cnt elimination.
//   Result 62.5->59.3us: balance gain (util ~97%) partially repaid by issue
//   stalls — VALUBusy 90->80 when residency halved to 4 waves/SIMD. The
//   per-eval critical path (~70-deep serial ARX + Horner + vcc-serialized
//   div) ~= per-wave issue demand, so 4 waves/SIMD leave gaps.
// R23 (perf only, THIS ROUND): 2-eval unroll — per-lane ILP.
//   Each round evaluates TWO sequential spikes: delta_k and delta_{k+1} are
//   independent of the running sum (only the compares chain), so two
//   independent threefry+log1pf pipelines interleave, doubling per-lane ILP
//   at unchanged wave count and pool balance (straggler advances 2/round ->
//   round-bound ~20 < ideal 21.7). Exit logic in RN-sequential order:
//   run1 = run+(q1+0.002f), run2 = run1+(q2+0.002f); first-crossing checks
//   run1>=1 -> s, run2>=1 -> s+1, s+2==100 -> 100. s stays even (kSpikes=100
//   even) so the odd-index cap check is vacuous. Wasted 2nd eval on odd-exit
//   elements (~+4.6% evals) vs halved loop overhead ~= volume-neutral.
//   Counter folded incrementally: jc = s<<20|o, jc += 2<<20 per round.
//   Same per-eval math in the same order -> bit-exact by construction.

static constexpr int      kElems  = 256 * 32 * 128;   // 1048576 = 2^20
static constexpr int      kSpikes = 100;              // NUM_SPIKES
static constexpr int      kBlocks = 1024;             // x256 thr = 4096 waves
static constexpr uint32_t kEPW    = 256;              // elements per wave

__device__ __forceinline__ uint32_t rotl32(uint32_t v, uint32_t d) {
  return (v << d) | (v >> (32u - d));
}

// threefry2x32 with key (0, 42) — matches jax.random.key(42).
__device__ __forceinline__ void threefry2x32_0_42(uint32_t x0, uint32_t x1,
                                                  uint32_t& o0, uint32_t& o1) {
  const uint32_t ks0 = 0u;
  const uint32_t ks1 = 42u;
  const uint32_t ks2 = 0x1BD11BDAu ^ 0u ^ 42u;
  uint32_t a = x0 + ks0;
  uint32_t b = x1 + ks1;
#define TF_ROUND(r) { a += b; b = rotl32(b, (r)); b ^= a; }
  TF_ROUND(13u) TF_ROUND(15u) TF_ROUND(26u) TF_ROUND(6u)
  a += ks1; b += ks2 + 1u;
  TF_ROUND(17u) TF_ROUND(29u) TF_ROUND(16u) TF_ROUND(24u)
  a += ks2; b += ks0 + 2u;
  TF_ROUND(13u) TF_ROUND(15u) TF_ROUND(26u) TF_ROUND(6u)
  a += ks0; b += ks1 + 3u;
  TF_ROUND(17u) TF_ROUND(29u) TF_ROUND(16u) TF_ROUND(24u)
  a += ks1; b += ks2 + 4u;
  TF_ROUND(13u) TF_ROUND(15u) TF_ROUND(26u) TF_ROUND(6u)
  a += ks2; b += ks0 + 5u;
#undef TF_ROUND
  o0 = a; o1 = b;
}

// Branchless fdlibm s_log1pf for x = -m*2^-23, m in [0, 2^23) — bit-exact
// (R12 port) with the c-correction removed (c == +0 on this input set,
// proof R17). One IEEE f32 div remains: s = f/(2+f).
__device__ __forceinline__ float fdlibm_log1pf_nb(float x) {
#pragma clang fp contract(off)
  const float ln2_hi = __uint_as_float(0x3f317180u);
  const float ln2_lo = __uint_as_float(0x3717f7d1u);
  const float Lp1 = __uint_as_float(0x3F2AAAABu);
  const float Lp2 = __uint_as_float(0x3ECCCCCDu);
  const float Lp3 = __uint_as_float(0x3E924925u);
  const float Lp4 = __uint_as_float(0x3E638E29u);
  const float Lp5 = __uint_as_float(0x3E3A3325u);
  const float Lp6 = __uint_as_float(0x3E1CD04Fu);
  const float Lp7 = __uint_as_float(0x3E178897u);

  uint32_t hx = __float_as_uint(x);
  uint32_t ax = hx & 0x7fffffffu;

  float u = 1.0f + x;
  uint32_t hu = __float_as_uint(u);
  int k = (int)(hu >> 23) - 127;
  uint32_t m = hu & 0x007fffffu;
  bool half = (m >= 0x3504f7u);
  int k2 = half ? (k + 1) : k;
  float u2 = __uint_as_float(m | (half ? 0x3f000000u : 0x3f800000u));
  float f2 = u2 - 1.0f;

  bool cond0 = ((int32_t)hx <= (int32_t)0xbe95f61fu);
  float kf = cond0 ? 0.0f : (float)k2;
  float ff = cond0 ? x : f2;

  float hfsq = (0.5f * ff) * ff;
  float s = ff / (2.0f + ff);             // f32 IEEE div (the only one left)
  float z = s * s;
  float R = z * (Lp1 + z * (Lp2 + z * (Lp3 + z * (Lp4 +
            z * (Lp5 + z * (Lp6 + z * Lp7))))));
  float lowsum = s * (hfsq + R) + kf * ln2_lo;
  float res = kf * ln2_hi - ((hfsq - lowsum) - ff);

  float tiny2 = x - (x * x) * 0.5f;
  res = (ax < 0x38000000u) ? ((ax < 0x33800000u) ? x : tiny2) : res;
  return res;
}

// One spike-interval delta for counter jc: bits -> uniform -> exponential
// -> / rate (f64-reciprocal mul) -> + refractory. Bit-exact original chain.
__device__ __forceinline__ float spike_delta(uint32_t jc, double inv_d) {
#pragma clang fp contract(off)
  uint32_t b1, b2;
  threefry2x32_0_42(0u, jc, b1, b2);
  uint32_t bits = b1 ^ b2;
  float uu = __uint_as_float((bits >> 9) | 0x3f800000u) - 1.0f;  // [0, 1)
  float expo = -fdlibm_log1pf_nb(-uu);
  float q = (float)((double)expo * inv_d);   // == expo / rate (IEEE f32)
  return q + 0.002f;
}

__global__ void __launch_bounds__(256) poisson_count_kernel(
    const float* __restrict__ rates, int* __restrict__ out) {
#pragma clang fp contract(off)
  __shared__ uint32_t pool_idx[4][kEPW];   // local element index (LPT order)
  __shared__ double   pool_inv[4][kEPW];   // hoisted 1.0/(double)rate
  int wslot = (int)threadIdx.x >> 6;
  int lane  = (int)threadIdx.x & 63;
  int wid   = blockIdx.x * 4 + wslot;
  uint32_t base = (uint32_t)wid * kEPW;
  uint64_t lmask_lt = (1ull << lane) - 1ull;

  // ---- one-time setup: LPT buckets + hoisted f64 reciprocals ----
  {
    float r[4];
    int   bb[4];
    uint32_t pos[4];
#pragma unroll
    for (int i = 0; i < 4; ++i) {
      r[i] = rates[base + (uint32_t)(i * 64) + (uint32_t)lane];
      int q = (int)(r[i] * 0.4f);
      q = q > 7 ? 7 : q;
      bb[i] = 7 - q;                       // bucket 0 = highest rates
    }
    uint32_t off = 0;
#pragma unroll
    for (int b = 0; b < 8; ++b) {
      uint64_t m0 = __ballot(bb[0] == b);
      uint64_t m1 = __ballot(bb[1] == b);
      uint64_t m2 = __ballot(bb[2] == b);
      uint64_t m3 = __ballot(bb[3] == b);
      uint32_t c0 = (uint32_t)__popcll(m0);
      uint32_t c1 = (uint32_t)__popcll(m1);
      uint32_t c2 = (uint32_t)__popcll(m2);
      uint32_t c3 = (uint32_t)__popcll(m3);
      if (bb[0] == b) pos[0] = off + (uint32_t)__popcll(m0 & lmask_lt);
      if (bb[1] == b) pos[1] = off + c0 + (uint32_t)__popcll(m1 & lmask_lt);
      if (bb[2] == b) pos[2] = off + c0 + c1 + (uint32_t)__popcll(m2 & lmask_lt);
      if (bb[3] == b) pos[3] = off + c0 + c1 + c2 + (uint32_t)__popcll(m3 & lmask_lt);
      off += c0 + c1 + c2 + c3;
    }
#pragma unroll
    for (int i = 0; i < 4; ++i) {
      pool_idx[wslot][pos[i]] = (uint32_t)(i * 64) + (uint32_t)lane;
      pool_inv[wslot][pos[i]] = 1.0 / (double)r[i];   // CR f64 recip, hoisted
    }
  }
  __syncthreads();

  // ---- main loop: ballot lane-refill; TWO sequential evals per round ----
  uint32_t next = 0;                       // wave-uniform: elements handed out
  uint32_t o = 0;
  uint32_t jc = 0;                         // threefry counter = (s<<20) + o
  float run = 0.0f;
  int s = 0;                               // evals consumed (always even)
  double inv_d = 0.0;
  bool active = false;

  while (true) {
    uint64_t needmask = __ballot(!active);
    if (needmask != 0ull) {
      uint32_t avail = kEPW - next;
      if (avail != 0u) {
        if (!active) {
          uint32_t rank = (uint32_t)__popcll(needmask & lmask_lt);
          if (rank < avail) {
            uint32_t slot = next + rank;
            o = base + pool_idx[wslot][slot];
            inv_d = pool_inv[wslot][slot];
            run = 0.0f; s = 0; jc = o;     // s=0 -> jc = o
            active = true;
          }
        }
        uint32_t nneed = (uint32_t)__popcll(needmask);
        next += (nneed < avail) ? nneed : avail;
      } else if (needmask == ~0ull) {
        break;                             // pool empty, all lanes idle
      }
    }

    if (active) {
      // Two independent delta pipelines (ILP x2); sequential RN cumsum.
      float d1 = spike_delta(jc, inv_d);             // eval s
      float d2 = spike_delta(jc + 0x100000u, inv_d); // eval s+1 (kElems=2^20)
      float run1 = run + d1;
      float run2 = run1 + d2;
      bool lt1 = (run1 < 1.0f);
      bool lt2 = (run2 < 1.0f);
      if (!lt1) {                          // crossed at eval s+1 -> count = s
        out[o] = s;
        active = false;
      } else if (!lt2) {                   // crossed at eval s+2 -> count = s+1
        out[o] = s + 1;
        active = false;
      } else if (s + 2 == kSpikes) {       // cap: 100 evals, all below 1
        out[o] = kSpikes;
        active = false;
      } else {
        run = run2;
        s += 2;
        jc += 0x200000u;                   // += 2*2^20
      }
    }
  }
}

extern "C" void kernel_launch(void* const* d_in, const int* in_sizes, int n_in,
                              void* d_out, int out_size, void* d_ws, size_t ws_size,
                              hipStream_t stream) {
  const float* rates = (const float*)d_in[0];
  int* out = (int*)d_out;
  (void)in_sizes; (void)n_in; (void)out_size; (void)d_ws; (void)ws_size;
  poisson_count_kernel<<<kBlocks, 256, 0, stream>>>(rates, out);
}

// Round 5
// 101.892 us; speedup vs baseline: 1.0629x; 1.0129x over previous
//
#include <hip/hip_runtime.h>
#include <stdint.h>

// PoissonNeuronTransform — bit-exact vs the harness's NUMPY reference (ref=np).
// Validated (absmax 0.0, R11-R18): threefry2x32 partitionable bits, uniform
// bit-trick, fdlibm log1pf port (dead c-branch removed, proof R17), +0.002f,
// sequential f32 cumsum, early exit (monotone RN-fadd), wave-internal ballot
// lane-refill, LPT (descending-rate) handout.
// R19: hoisted per-element f64 reciprocal into setup (LDS).
// R20: __launch_bounds__(256,8) — NO-OP (VGPR_Count=12 raw; never limited).
// R21/22: kEPW=256 (1024 blocks) straggler amortization + cnt elimination.
//   62.5->59.3us; VALUBusy 90->80 at 4 waves/SIMD.
// R23: 2-eval unroll (per-lane ILP). 59.3->57.4us only: counters show we are
//   near the VALU EXECUTION-occupancy floor (pipe-busy ~2.4x pure-issue
//   estimate => multi-cycle ops dominate: f64 cvt/mul chain ~8-10cyc at the
//   half-rate f64 pipe + f32 IEEE-div sequence). ILP can't remove those.
// R24 (perf only, THIS ROUND): cycle diet on the multi-cycle tail.
//   (a) Markstein CR division replaces the f64 reciprocal-multiply:
//       y = RN(1/r) hoisted per element (f64 in setup, CR f32 reciprocal);
//       per eval q0 = x*y; rr = fmaf(-r,q0,x); q = fmaf(rr,y,q0).
//       Markstein's theorem (RN + fma + CR reciprocal, normal range) gives
//       q == RN(x/r) == the reference's correctly-rounded f32 division.
//       Removes ALL f64 from the loop: ~8-10 cyc -> 3 full-rate f32 ops.
//   (b) Branchless exit: d2>0 => (lt2 => lt1), so the 3-way else-if chain
//       collapses to one exit branch, count = lt2 ? 100 : (lt1 ? s-1 : s-2).
//   Same eval math producing identical f32 bits -> bit-exact.

static constexpr int      kElems  = 256 * 32 * 128;   // 1048576 = 2^20
static constexpr int      kSpikes = 100;              // NUM_SPIKES
static constexpr int      kBlocks = 1024;             // x256 thr = 4096 waves
static constexpr uint32_t kEPW    = 256;              // elements per wave

__device__ __forceinline__ uint32_t rotl32(uint32_t v, uint32_t d) {
  return (v << d) | (v >> (32u - d));
}

// threefry2x32 with key (0, 42) — matches jax.random.key(42).
__device__ __forceinline__ void threefry2x32_0_42(uint32_t x0, uint32_t x1,
                                                  uint32_t& o0, uint32_t& o1) {
  const uint32_t ks0 = 0u;
  const uint32_t ks1 = 42u;
  const uint32_t ks2 = 0x1BD11BDAu ^ 0u ^ 42u;
  uint32_t a = x0 + ks0;
  uint32_t b = x1 + ks1;
#define TF_ROUND(r) { a += b; b = rotl32(b, (r)); b ^= a; }
  TF_ROUND(13u) TF_ROUND(15u) TF_ROUND(26u) TF_ROUND(6u)
  a += ks1; b += ks2 + 1u;
  TF_ROUND(17u) TF_ROUND(29u) TF_ROUND(16u) TF_ROUND(24u)
  a += ks2; b += ks0 + 2u;
  TF_ROUND(13u) TF_ROUND(15u) TF_ROUND(26u) TF_ROUND(6u)
  a += ks0; b += ks1 + 3u;
  TF_ROUND(17u) TF_ROUND(29u) TF_ROUND(16u) TF_ROUND(24u)
  a += ks1; b += ks2 + 4u;
  TF_ROUND(13u) TF_ROUND(15u) TF_ROUND(26u) TF_ROUND(6u)
  a += ks2; b += ks0 + 5u;
#undef TF_ROUND
  o0 = a; o1 = b;
}

// Branchless fdlibm s_log1pf for x = -m*2^-23, m in [0, 2^23) — bit-exact
// (R12 port) with the c-correction removed (c == +0 on this input set,
// proof R17). One IEEE f32 div remains: s = f/(2+f).
__device__ __forceinline__ float fdlibm_log1pf_nb(float x) {
#pragma clang fp contract(off)
  const float ln2_hi = __uint_as_float(0x3f317180u);
  const float ln2_lo = __uint_as_float(0x3717f7d1u);
  const float Lp1 = __uint_as_float(0x3F2AAAABu);
  const float Lp2 = __uint_as_float(0x3ECCCCCDu);
  const float Lp3 = __uint_as_float(0x3E924925u);
  const float Lp4 = __uint_as_float(0x3E638E29u);
  const float Lp5 = __uint_as_float(0x3E3A3325u);
  const float Lp6 = __uint_as_float(0x3E1CD04Fu);
  const float Lp7 = __uint_as_float(0x3E178897u);

  uint32_t hx = __float_as_uint(x);
  uint32_t ax = hx & 0x7fffffffu;

  float u = 1.0f + x;
  uint32_t hu = __float_as_uint(u);
  int k = (int)(hu >> 23) - 127;
  uint32_t m = hu & 0x007fffffu;
  bool half = (m >= 0x3504f7u);
  int k2 = half ? (k + 1) : k;
  float u2 = __uint_as_float(m | (half ? 0x3f000000u : 0x3f800000u));
  float f2 = u2 - 1.0f;

  bool cond0 = ((int32_t)hx <= (int32_t)0xbe95f61fu);
  float kf = cond0 ? 0.0f : (float)k2;
  float ff = cond0 ? x : f2;

  float hfsq = (0.5f * ff) * ff;
  float s = ff / (2.0f + ff);             // f32 IEEE div (the only one left)
  float z = s * s;
  float R = z * (Lp1 + z * (Lp2 + z * (Lp3 + z * (Lp4 +
            z * (Lp5 + z * (Lp6 + z * Lp7))))));
  float lowsum = s * (hfsq + R) + kf * ln2_lo;
  float res = kf * ln2_hi - ((hfsq - lowsum) - ff);

  float tiny2 = x - (x * x) * 0.5f;
  res = (ax < 0x38000000u) ? ((ax < 0x33800000u) ? x : tiny2) : res;
  return res;
}

// One spike-interval delta for counter jc: bits -> uniform -> exponential
// -> / rate via Markstein CR division (rt = rate, ry = RN(1/rt)) -> + 0.002.
// Markstein (RN + fma + CR reciprocal): q == RN(expo/rt), the reference's
// correctly-rounded f32 division. Bit-exact original chain.
__device__ __forceinline__ float spike_delta(uint32_t jc, float rt, float ry) {
#pragma clang fp contract(off)
  uint32_t b1, b2;
  threefry2x32_0_42(0u, jc, b1, b2);
  uint32_t bits = b1 ^ b2;
  float uu = __uint_as_float((bits >> 9) | 0x3f800000u) - 1.0f;  // [0, 1)
  float expo = -fdlibm_log1pf_nb(-uu);
  float q0 = expo * ry;
  float rr = fmaf(-rt, q0, expo);          // exact residual (fma)
  float q  = fmaf(rr, ry, q0);             // == RN(expo/rt)
  return q + 0.002f;
}

__global__ void __launch_bounds__(256) poisson_count_kernel(
    const float* __restrict__ rates, int* __restrict__ out) {
#pragma clang fp contract(off)
  __shared__ uint32_t pool_idx[4][kEPW];   // local element index (LPT order)
  __shared__ float2   pool_ry[4][kEPW];    // {rate, RN(1/rate)} per element
  int wslot = (int)threadIdx.x >> 6;
  int lane  = (int)threadIdx.x & 63;
  int wid   = blockIdx.x * 4 + wslot;
  uint32_t base = (uint32_t)wid * kEPW;
  uint64_t lmask_lt = (1ull << lane) - 1ull;

  // ---- one-time setup: LPT buckets + hoisted CR f32 reciprocals ----
  {
    float r[4];
    int   bb[4];
    uint32_t pos[4];
#pragma unroll
    for (int i = 0; i < 4; ++i) {
      r[i] = rates[base + (uint32_t)(i * 64) + (uint32_t)lane];
      int q = (int)(r[i] * 0.4f);
      q = q > 7 ? 7 : q;
      bb[i] = 7 - q;                       // bucket 0 = highest rates
    }
    uint32_t off = 0;
#pragma unroll
    for (int b = 0; b < 8; ++b) {
      uint64_t m0 = __ballot(bb[0] == b);
      uint64_t m1 = __ballot(bb[1] == b);
      uint64_t m2 = __ballot(bb[2] == b);
      uint64_t m3 = __ballot(bb[3] == b);
      uint32_t c0 = (uint32_t)__popcll(m0);
      uint32_t c1 = (uint32_t)__popcll(m1);
      uint32_t c2 = (uint32_t)__popcll(m2);
      uint32_t c3 = (uint32_t)__popcll(m3);
      if (bb[0] == b) pos[0] = off + (uint32_t)__popcll(m0 & lmask_lt);
      if (bb[1] == b) pos[1] = off + c0 + (uint32_t)__popcll(m1 & lmask_lt);
      if (bb[2] == b) pos[2] = off + c0 + c1 + (uint32_t)__popcll(m2 & lmask_lt);
      if (bb[3] == b) pos[3] = off + c0 + c1 + c2 + (uint32_t)__popcll(m3 & lmask_lt);
      off += c0 + c1 + c2 + c3;
    }
#pragma unroll
    for (int i = 0; i < 4; ++i) {
      pool_idx[wslot][pos[i]] = (uint32_t)(i * 64) + (uint32_t)lane;
      // CR f32 reciprocal via f64 (setup-only f64; none in the main loop)
      pool_ry[wslot][pos[i]] = make_float2(r[i], (float)(1.0 / (double)r[i]));
    }
  }
  __syncthreads();

  // ---- main loop: ballot lane-refill; TWO sequential evals per round ----
  uint32_t next = 0;                       // wave-uniform: elements handed out
  uint32_t o = 0;
  uint32_t jc = 0;                         // threefry counter = (s<<20) + o
  float run = 0.0f;
  int s = 0;                               // evals consumed (always even)
  float rt = 1.0f, ry = 1.0f;              // rate, RN(1/rate)
  bool active = false;

  while (true) {
    uint64_t needmask = __ballot(!active);
    if (needmask != 0ull) {
      uint32_t avail = kEPW - next;
      if (avail != 0u) {
        if (!active) {
          uint32_t rank = (uint32_t)__popcll(needmask & lmask_lt);
          if (rank < avail) {
            uint32_t slot = next + rank;
            o = base + pool_idx[wslot][slot];
            float2 ryv = pool_ry[wslot][slot];
            rt = ryv.x; ry = ryv.y;
            run = 0.0f; s = 0; jc = o;     // s=0 -> jc = o
            active = true;
          }
        }
        uint32_t nneed = (uint32_t)__popcll(needmask);
        next += (nneed < avail) ? nneed : avail;
      } else if (needmask == ~0ull) {
        break;                             // pool empty, all lanes idle
      }
    }

    if (active) {
      // Two independent delta pipelines (ILP x2); sequential RN cumsum.
      float d1 = spike_delta(jc, rt, ry);             // eval s
      float d2 = spike_delta(jc + 0x100000u, rt, ry); // eval s+1 (2^20)
      float run1 = run + d1;
      float run2 = run1 + d2;
      s += 2;
      bool lt1 = (run1 < 1.0f);
      bool lt2 = (run2 < 1.0f);
      // monotone: d2 > 0 => (lt2 => lt1); single exit branch.
      if (!lt2 || s == kSpikes) {
        // count: crossed in this pair -> lt1 ? s-1 : s-2; else cap -> 100.
        out[o] = lt2 ? kSpikes : (lt1 ? (s - 1) : (s - 2));
        active = false;
      } else {
        run = run2;
        jc += 0x200000u;                   // += 2*2^20
      }
    }
  }
}

extern "C" void kernel_launch(void* const* d_in, const int* in_sizes, int n_in,
                              void* d_out, int out_size, void* d_ws, size_t ws_size,
                              hipStream_t stream) {
  const float* rates = (const float*)d_in[0];
  int* out = (int*)d_out;
  (void)in_sizes; (void)n_in; (void)out_size; (void)d_ws; (void)ws_size;
  poisson_count_kernel<<<kBlocks, 256, 0, stream>>>(rates, out);
}

// Round 6
// 100.466 us; speedup vs baseline: 1.0780x; 1.0142x over previous
//
#include <hip/hip_runtime.h>
#include <stdint.h>

// PoissonNeuronTransform — bit-exact vs the harness's NUMPY reference (ref=np).
// Validated (absmax 0.0, R11-R18): threefry2x32 partitionable bits, uniform
// bit-trick, fdlibm log1pf port (dead c-branch removed, proof R17), +0.002f,
// sequential f32 cumsum, early exit (monotone RN-fadd), wave-internal ballot
// lane-refill, LPT (descending-rate) handout.
// R19: hoisted per-element f64 reciprocal into setup (LDS).
// R20: __launch_bounds__(256,8) — NO-OP (VGPR_Count=12 raw; never limited).
// R21/22: kEPW=256 (1024 blocks) straggler amortization + cnt elimination.
//   62.5->59.3us; VALUBusy 90->80 at 4 waves/SIMD.
// R23: 2-eval unroll (per-lane ILP). 59.3->57.4us.
// R24: Markstein CR division by rate (f64 removed from loop) + branchless
//   exit. 57.4->58.7: busy fell (83->78) but dur rose — we are mixed
//   latency/issue-bound at 4 waves/SIMD; serial fma chains lengthen the
//   critical path even as they cut busy cycles.
// R25 (perf only, THIS ROUND): Markstein division INSIDE log1pf.
//   The IEEE f32 div (s = ff/(2+ff)) emits v_div_scale/v_rcp/v_div_fmas/
//   v_div_fixup (~10 inst) — and div_scale WRITES vcc while div_fmas READS
//   vcc, so the two ILP eval-chains SERIALIZE through the wave's single vcc
//   in exactly the region ILP-2 needs overlapped. Replace with
//   domain-restricted Markstein: den=2+ff in [1.707,2.414] (normal), result
//   only matters for |ff| >= 2^-15 (tiny path overridden by final cndmask):
//   y0=v_rcp_f32 (<=1ulp); 1 exact-fma NR step -> y1 err ~2^-25;
//   q0=ff*y1; r=fma(-den,q0,ff); s=fma(r,y1,q0) == RN(ff/den) (Markstein).
//   6 vcc-free full-rate inst, chains fully independent. Bit-exact by
//   theorem over the live domain; absmax=0 required, else revert.

static constexpr int      kElems  = 256 * 32 * 128;   // 1048576 = 2^20
static constexpr int      kSpikes = 100;              // NUM_SPIKES
static constexpr int      kBlocks = 1024;             // x256 thr = 4096 waves
static constexpr uint32_t kEPW    = 256;              // elements per wave

__device__ __forceinline__ uint32_t rotl32(uint32_t v, uint32_t d) {
  return (v << d) | (v >> (32u - d));
}

// threefry2x32 with key (0, 42) — matches jax.random.key(42).
__device__ __forceinline__ void threefry2x32_0_42(uint32_t x0, uint32_t x1,
                                                  uint32_t& o0, uint32_t& o1) {
  const uint32_t ks0 = 0u;
  const uint32_t ks1 = 42u;
  const uint32_t ks2 = 0x1BD11BDAu ^ 0u ^ 42u;
  uint32_t a = x0 + ks0;
  uint32_t b = x1 + ks1;
#define TF_ROUND(r) { a += b; b = rotl32(b, (r)); b ^= a; }
  TF_ROUND(13u) TF_ROUND(15u) TF_ROUND(26u) TF_ROUND(6u)
  a += ks1; b += ks2 + 1u;
  TF_ROUND(17u) TF_ROUND(29u) TF_ROUND(16u) TF_ROUND(24u)
  a += ks2; b += ks0 + 2u;
  TF_ROUND(13u) TF_ROUND(15u) TF_ROUND(26u) TF_ROUND(6u)
  a += ks0; b += ks1 + 3u;
  TF_ROUND(17u) TF_ROUND(29u) TF_ROUND(16u) TF_ROUND(24u)
  a += ks1; b += ks2 + 4u;
  TF_ROUND(13u) TF_ROUND(15u) TF_ROUND(26u) TF_ROUND(6u)
  a += ks2; b += ks0 + 5u;
#undef TF_ROUND
  o0 = a; o1 = b;
}

// Branchless fdlibm s_log1pf for x = -m*2^-23, m in [0, 2^23) — bit-exact
// (R12 port; c-branch removed, proof R17). R25: the one IEEE f32 div
// (s = f/(2+f)) replaced by vcc-free Markstein division (CR over the live
// domain: den in [1.707,2.414] normal; quotient only consumed when
// |ff| >= 2^-15 since smaller |x| is overridden by the tiny-path selects).
__device__ __forceinline__ float fdlibm_log1pf_nb(float x) {
#pragma clang fp contract(off)
  const float ln2_hi = __uint_as_float(0x3f317180u);
  const float ln2_lo = __uint_as_float(0x3717f7d1u);
  const float Lp1 = __uint_as_float(0x3F2AAAABu);
  const float Lp2 = __uint_as_float(0x3ECCCCCDu);
  const float Lp3 = __uint_as_float(0x3E924925u);
  const float Lp4 = __uint_as_float(0x3E638E29u);
  const float Lp5 = __uint_as_float(0x3E3A3325u);
  const float Lp6 = __uint_as_float(0x3E1CD04Fu);
  const float Lp7 = __uint_as_float(0x3E178897u);

  uint32_t hx = __float_as_uint(x);
  uint32_t ax = hx & 0x7fffffffu;

  float u = 1.0f + x;
  uint32_t hu = __float_as_uint(u);
  int k = (int)(hu >> 23) - 127;
  uint32_t m = hu & 0x007fffffu;
  bool half = (m >= 0x3504f7u);
  int k2 = half ? (k + 1) : k;
  float u2 = __uint_as_float(m | (half ? 0x3f000000u : 0x3f800000u));
  float f2 = u2 - 1.0f;

  bool cond0 = ((int32_t)hx <= (int32_t)0xbe95f61fu);
  float kf = cond0 ? 0.0f : (float)k2;
  float ff = cond0 ? x : f2;

  float hfsq = (0.5f * ff) * ff;
  // Markstein division s = RN(ff / (2+ff)), vcc-free (R25):
  float den = 2.0f + ff;
  float y0 = __builtin_amdgcn_rcpf(den);   // v_rcp_f32, <=1 ulp
  float e  = fmaf(-den, y0, 1.0f);         // exact-fma residual
  float y1 = fmaf(y0, e, y0);              // reciprocal err ~2^-25
  float q0 = ff * y1;
  float r1 = fmaf(-den, q0, ff);           // exact residual
  float s  = fmaf(r1, y1, q0);             // == RN(ff/den), Markstein
  float z = s * s;
  float R = z * (Lp1 + z * (Lp2 + z * (Lp3 + z * (Lp4 +
            z * (Lp5 + z * (Lp6 + z * Lp7))))));
  float lowsum = s * (hfsq + R) + kf * ln2_lo;
  float res = kf * ln2_hi - ((hfsq - lowsum) - ff);

  float tiny2 = x - (x * x) * 0.5f;
  res = (ax < 0x38000000u) ? ((ax < 0x33800000u) ? x : tiny2) : res;
  return res;
}

// One spike-interval delta for counter jc: bits -> uniform -> exponential
// -> / rate via Markstein CR division (rt = rate, ry = RN(1/rt)) -> + 0.002.
// Markstein (RN + fma + CR reciprocal): q == RN(expo/rt), the reference's
// correctly-rounded f32 division. Bit-exact original chain.
__device__ __forceinline__ float spike_delta(uint32_t jc, float rt, float ry) {
#pragma clang fp contract(off)
  uint32_t b1, b2;
  threefry2x32_0_42(0u, jc, b1, b2);
  uint32_t bits = b1 ^ b2;
  float uu = __uint_as_float((bits >> 9) | 0x3f800000u) - 1.0f;  // [0, 1)
  float expo = -fdlibm_log1pf_nb(-uu);
  float q0 = expo * ry;
  float rr = fmaf(-rt, q0, expo);          // exact residual (fma)
  float q  = fmaf(rr, ry, q0);             // == RN(expo/rt)
  return q + 0.002f;
}

__global__ void __launch_bounds__(256) poisson_count_kernel(
    const float* __restrict__ rates, int* __restrict__ out) {
#pragma clang fp contract(off)
  __shared__ uint32_t pool_idx[4][kEPW];   // local element index (LPT order)
  __shared__ float2   pool_ry[4][kEPW];    // {rate, RN(1/rate)} per element
  int wslot = (int)threadIdx.x >> 6;
  int lane  = (int)threadIdx.x & 63;
  int wid   = blockIdx.x * 4 + wslot;
  uint32_t base = (uint32_t)wid * kEPW;
  uint64_t lmask_lt = (1ull << lane) - 1ull;

  // ---- one-time setup: LPT buckets + hoisted CR f32 reciprocals ----
  {
    float r[4];
    int   bb[4];
    uint32_t pos[4];
#pragma unroll
    for (int i = 0; i < 4; ++i) {
      r[i] = rates[base + (uint32_t)(i * 64) + (uint32_t)lane];
      int q = (int)(r[i] * 0.4f);
      q = q > 7 ? 7 : q;
      bb[i] = 7 - q;                       // bucket 0 = highest rates
    }
    uint32_t off = 0;
#pragma unroll
    for (int b = 0; b < 8; ++b) {
      uint64_t m0 = __ballot(bb[0] == b);
      uint64_t m1 = __ballot(bb[1] == b);
      uint64_t m2 = __ballot(bb[2] == b);
      uint64_t m3 = __ballot(bb[3] == b);
      uint32_t c0 = (uint32_t)__popcll(m0);
      uint32_t c1 = (uint32_t)__popcll(m1);
      uint32_t c2 = (uint32_t)__popcll(m2);
      uint32_t c3 = (uint32_t)__popcll(m3);
      if (bb[0] == b) pos[0] = off + (uint32_t)__popcll(m0 & lmask_lt);
      if (bb[1] == b) pos[1] = off + c0 + (uint32_t)__popcll(m1 & lmask_lt);
      if (bb[2] == b) pos[2] = off + c0 + c1 + (uint32_t)__popcll(m2 & lmask_lt);
      if (bb[3] == b) pos[3] = off + c0 + c1 + c2 + (uint32_t)__popcll(m3 & lmask_lt);
      off += c0 + c1 + c2 + c3;
    }
#pragma unroll
    for (int i = 0; i < 4; ++i) {
      pool_idx[wslot][pos[i]] = (uint32_t)(i * 64) + (uint32_t)lane;
      // CR f32 reciprocal via f64 (setup-only f64; none in the main loop)
      pool_ry[wslot][pos[i]] = make_float2(r[i], (float)(1.0 / (double)r[i]));
    }
  }
  __syncthreads();

  // ---- main loop: ballot lane-refill; TWO sequential evals per round ----
  uint32_t next = 0;                       // wave-uniform: elements handed out
  uint32_t o = 0;
  uint32_t jc = 0;                         // threefry counter = (s<<20) + o
  float run = 0.0f;
  int s = 0;                               // evals consumed (always even)
  float rt = 1.0f, ry = 1.0f;              // rate, RN(1/rate)
  bool active = false;

  while (true) {
    uint64_t needmask = __ballot(!active);
    if (needmask != 0ull) {
      uint32_t avail = kEPW - next;
      if (avail != 0u) {
        if (!active) {
          uint32_t rank = (uint32_t)__popcll(needmask & lmask_lt);
          if (rank < avail) {
            uint32_t slot = next + rank;
            o = base + pool_idx[wslot][slot];
            float2 ryv = pool_ry[wslot][slot];
            rt = ryv.x; ry = ryv.y;
            run = 0.0f; s = 0; jc = o;     // s=0 -> jc = o
            active = true;
          }
        }
        uint32_t nneed = (uint32_t)__popcll(needmask);
        next += (nneed < avail) ? nneed : avail;
      } else if (needmask == ~0ull) {
        break;                             // pool empty, all lanes idle
      }
    }

    if (active) {
      // Two independent delta pipelines (ILP x2); sequential RN cumsum.
      float d1 = spike_delta(jc, rt, ry);             // eval s
      float d2 = spike_delta(jc + 0x100000u, rt, ry); // eval s+1 (2^20)
      float run1 = run + d1;
      float run2 = run1 + d2;
      s += 2;
      bool lt1 = (run1 < 1.0f);
      bool lt2 = (run2 < 1.0f);
      // monotone: d2 > 0 => (lt2 => lt1); single exit branch.
      if (!lt2 || s == kSpikes) {
        // count: crossed in this pair -> lt1 ? s-1 : s-2; else cap -> 100.
        out[o] = lt2 ? kSpikes : (lt1 ? (s - 1) : (s - 2));
        active = false;
      } else {
        run = run2;
        jc += 0x200000u;                   // += 2*2^20
      }
    }
  }
}

extern "C" void kernel_launch(void* const* d_in, const int* in_sizes, int n_in,
                              void* d_out, int out_size, void* d_ws, size_t ws_size,
                              hipStream_t stream) {
  const float* rates = (const float*)d_in[0];
  int* out = (int*)d_out;
  (void)in_sizes; (void)n_in; (void)out_size; (void)d_ws; (void)ws_size;
  poisson_count_kernel<<<kBlocks, 256, 0, stream>>>(rates, out);
}